// Round 7
// baseline (172.612 us; speedup 1.0000x reference)
//
#include <hip/hip_runtime.h>
#include <math.h>

// Problem constants (B=8, S=512, T=4, D=128)
constexpr int M     = 16384;     // keys = B*S*T
constexpr int NANCH = 12288;     // anchors = B*S*(T-1)
constexpr int ELEM  = 2097152;   // B*S*T*D

typedef __bf16 bf16x8 __attribute__((ext_vector_type(8)));
typedef float f32x4 __attribute__((ext_vector_type(4)));
typedef unsigned int uint;

// bf16 slot layout (16B uint4 slots): slot(row r, chunk c) = (r>>4)*256 + c*16 + (r&15)
// -> MFMA fragment read = base + lane*16B (linear, conflict-free), staging is identity.

__device__ inline float waveRedSum(float v) {
#pragma unroll
  for (int off = 32; off > 0; off >>= 1) v += __shfl_down(v, off, 64);
  return v;
}

__device__ inline unsigned short f2bf(float x) {  // RNE
  unsigned int u = __float_as_uint(x);
  u += 0x7FFF + ((u >> 16) & 1);
  return (unsigned short)(u >> 16);
}
__device__ inline uint packbf(float x, float y) {
  return ((uint)f2bf(y) << 16) | (uint)f2bf(x);
}

__device__ inline float fast_exp2(float x) {  // v_exp_f32: 2^x
  float r;
  asm("v_exp_f32 %0, %1" : "=v"(r) : "v"(x));
  return r;
}

__device__ inline void load_lds16(uint4* lds, const uint4* g) {
  __builtin_amdgcn_global_load_lds(
      (const __attribute__((address_space(1))) unsigned int*)g,
      (__attribute__((address_space(3))) unsigned int*)lds, 16, 0, 0);
}

// unpack 8 bf16, multiply by scalar, repack (per-lane row rescale K -> A)
__device__ inline bf16x8 rescale8(uint4 raw, float rcp) {
  union { uint4 u4; uint us[4]; } v;
  v.u4 = raw;
  union { uint us[4]; bf16x8 b; } o;
#pragma unroll
  for (int n = 0; n < 4; ++n) {
    float lo = __uint_as_float(v.us[n] << 16);
    float hi = __uint_as_float(v.us[n] & 0xFFFF0000u);
    o.us[n] = packbf(lo * rcp, hi * rcp);
  }
  return o.b;
}

// ---------------- K1: fused prep (1024 blocks x 16 rows) ----------------
// Coalesced H load -> per-row sumsq -> scale; bf16 convert (scale folded) via
// LDS transpose -> coalesced uint4 Ksw store. Plus spike/mem^2 partials.
__global__ __launch_bounds__(256) void k_prep(
    const float* __restrict__ H, const float* __restrict__ spikes,
    const float* __restrict__ mem, uint* __restrict__ Ksw,
    float* __restrict__ scale, float* __restrict__ Pspike, float* __restrict__ Pmem) {
  __shared__ float ps[512];
  __shared__ float scb[16];
  __shared__ uint tb[1024];     // 16 rows x 64 uints in slot order
  __shared__ float buf2[2][4];
  const int g = blockIdx.x, t = threadIdx.x;

  const float4* H4 = (const float4*)H + (size_t)g * 512;
  float4 fa = H4[t];
  float4 fb = H4[t + 256];
  ps[t]       = fa.x * fa.x + fa.y * fa.y + fa.z * fa.z + fa.w * fa.w;
  ps[t + 256] = fb.x * fb.x + fb.y * fb.y + fb.z * fb.z + fb.w * fb.w;
  __syncthreads();
  if (t < 16) {
    float ss = 0.f;
#pragma unroll
    for (int j = 0; j < 32; ++j) ss += ps[t * 32 + ((j + t) & 31)];  // rotated, conflict-free
    float sc = 10.0f / fmaxf(sqrtf(ss), 1e-12f);
    scb[t] = sc;
    scale[g * 16 + t] = sc;
  }
  __syncthreads();

  const int ja = t & 31;                    // float4 index within row
  const int rla = t >> 5, rlb = 8 + (t >> 5);
  {
    float sa = scb[rla];
    uint2 ka = {packbf(fa.x * sa, fa.y * sa), packbf(fa.z * sa, fa.w * sa)};
    *(uint2*)&tb[((ja >> 1) * 16 + rla) * 4 + (ja & 1) * 2] = ka;
    float sb = scb[rlb];
    uint2 kb = {packbf(fb.x * sb, fb.y * sb), packbf(fb.z * sb, fb.w * sb)};
    *(uint2*)&tb[((ja >> 1) * 16 + rlb) * 4 + (ja & 1) * 2] = kb;
  }
  __syncthreads();
  ((uint4*)Ksw)[(size_t)g * 256 + t] = ((const uint4*)tb)[t];  // coalesced 4 KB

  // spikes mean + mem^2 partials (512 float4 each per block)
  const float4* s4 = (const float4*)spikes + (size_t)g * 512;
  const float4* m4 = (const float4*)mem + (size_t)g * 512;
  float4 s0 = s4[t], s1 = s4[t + 256];
  float4 m0 = m4[t], m1 = m4[t + 256];
  float ssp = s0.x + s0.y + s0.z + s0.w + s1.x + s1.y + s1.z + s1.w;
  float smm = m0.x * m0.x + m0.y * m0.y + m0.z * m0.z + m0.w * m0.w +
              m1.x * m1.x + m1.y * m1.y + m1.z * m1.z + m1.w * m1.w;
  ssp = waveRedSum(ssp);
  smm = waveRedSum(smm);
  int w = t >> 6, lane = t & 63;
  if (lane == 0) { buf2[0][w] = ssp; buf2[1][w] = smm; }
  __syncthreads();
  if (t == 0) {
    Pspike[g] = buf2[0][0] + buf2[0][1] + buf2[0][2] + buf2[0][3];
    Pmem[g]   = buf2[1][0] + buf2[1][1] + buf2[1][2] + buf2[1][3];
  }
}

// ---------------- K2: MFMA sim-GEMM + fused exp + row-sum ----------------
// 128 anchors x 1024 keys per block. A-fragments gathered from global Ksw
// (L2-hot) and rescaled by 1/scale (per-lane scalar) -> no A staging at all.
// Double-buffered 32 KB K tiles, prefetch-before-compute, 1 barrier/tile.
constexpr int KSPLIT = 16;
constexpr int KEYS_PB = M / KSPLIT;   // 1024
constexpr int NT = KEYS_PB / 128;     // 8

__global__ __launch_bounds__(256, 2) void k_sim(
    const uint4* __restrict__ Ksw, const float* __restrict__ scale,
    float* __restrict__ sumexp) {
  __shared__ uint4 Tile[4096];  // buf0 = [0,2048), buf1 = [2048,4096)
  const int tid = threadIdx.x;
  const int lane = tid & 63, w = tid >> 6;
  const int wm = w & 1, wn = w >> 1;
  const int wmo = wm * 64;
  const int a0 = blockIdx.y * 128;
  const int k0 = blockIdx.x * KEYS_PB;
  const int lcol = lane & 15, lhi = lane >> 4;

  // prefetch K tile 0 -> buf1 (loop parity: t2=0 computes from buf1)
  {
    const uint4* srcK = Ksw + (size_t)k0 * 16;
#pragma unroll
    for (int it = 0; it < 8; ++it)
      load_lds16(Tile + 2048 + it * 256 + tid, srcK + it * 256 + tid);
  }

  // A fragments: per-lane global gather from Ksw + rescale to un-normalized
  bf16x8 af[4][4];
#pragma unroll
  for (int mi = 0; mi < 4; ++mi) {
    int a = a0 + wmo + mi * 16 + lcol;
    int ar = (a / 3) * 4 + (a % 3);           // anchor -> H row
    float rcp = 1.0f / scale[ar];
    const uint4* base = Ksw + (size_t)(ar >> 4) * 256 + (ar & 15);
#pragma unroll
    for (int ks = 0; ks < 4; ++ks)
      af[mi][ks] = rescale8(base[(ks * 4 + lhi) * 16], rcp);
  }
  // -Mi*log2e for my C-layout rows (row = lhi*4 + r)
  float nmiL[4][4];
#pragma unroll
  for (int mi = 0; mi < 4; ++mi)
#pragma unroll
    for (int r = 0; r < 4; ++r) {
      int a = a0 + wmo + mi * 16 + lhi * 4 + r;
      int ar = (a / 3) * 4 + (a % 3);
      nmiL[mi][r] = -144.269504088896f / scale[ar];  // (100/sc)*log2e
    }
  __syncthreads();  // tile 0 staged (vmcnt drained by barrier)

  float rs[4][4] = {};
  for (int t2 = 0; t2 < NT; ++t2) {
    uint4* cur = Tile + ((t2 & 1) ? 0 : 2048);
    uint4* nxt = Tile + ((t2 & 1) ? 2048 : 0);
    if (t2 + 1 < NT) {  // prefetch next tile while computing this one
      const uint4* src = Ksw + ((size_t)k0 + (t2 + 1) * 128) * 16;
#pragma unroll
      for (int it = 0; it < 8; ++it)
        load_lds16(nxt + it * 256 + tid, src + it * 256 + tid);
    }
    f32x4 acc[4][4] = {};
#pragma unroll
    for (int ks = 0; ks < 4; ++ks) {
      bf16x8 bfr[4];
#pragma unroll
      for (int nj = 0; nj < 4; ++nj)
        bfr[nj] = *(const bf16x8*)(cur + (wn * 4 + nj) * 256 + ks * 64 + lane);
#pragma unroll
      for (int mi = 0; mi < 4; ++mi)
#pragma unroll
        for (int nj = 0; nj < 4; ++nj)
          acc[mi][nj] = __builtin_amdgcn_mfma_f32_16x16x32_bf16(af[mi][ks], bfr[nj], acc[mi][nj], 0, 0, 0);
    }
    // fused epilogue: rs += 2^(sim*log2e - Mi*log2e)
#pragma unroll
    for (int mi = 0; mi < 4; ++mi)
#pragma unroll
      for (int nj = 0; nj < 4; ++nj)
#pragma unroll
        for (int r = 0; r < 4; ++r)
          rs[mi][r] += fast_exp2(fmaf(acc[mi][nj][r], 1.44269504088896f, nmiL[mi][r]));
    __syncthreads();  // cur reads done + nxt staged
  }

  // reduce over 16 key-columns, one atomic per anchor per wave
#pragma unroll
  for (int mi = 0; mi < 4; ++mi)
#pragma unroll
    for (int r = 0; r < 4; ++r) {
      float v = rs[mi][r];
      v += __shfl_xor(v, 1, 64);
      v += __shfl_xor(v, 2, 64);
      v += __shfl_xor(v, 4, 64);
      v += __shfl_xor(v, 8, 64);
      if (lcol == 0) atomicAdd(&sumexp[a0 + wmo + mi * 16 + lhi * 4 + r], v);
    }
}

// ---------------- K3: diagonal + ce partials + last-block finalize ----------------
__global__ __launch_bounds__(256) void k_fin(
    const float* __restrict__ H, const float* __restrict__ scale,
    const float* __restrict__ sumexp, const int* __restrict__ targets,
    float* __restrict__ Pce, float* __restrict__ Pnv,
    const float* __restrict__ Pspike, const float* __restrict__ Pmem,
    uint* __restrict__ cnt, float* __restrict__ out) {
  int w = threadIdx.x >> 6, lane = threadIdx.x & 63;
  int abase = blockIdx.x * 16 + w * 4;

  // batched loads (ILP), then 4 interleaved wave reductions
  float d[4];
#pragma unroll
  for (int ii = 0; ii < 4; ++ii) {
    int i = abase + ii;
    int arow = (i / 3) * 4 + (i % 3);
    float2 a = *(const float2*)(H + (size_t)arow * 128 + lane * 2);
    float2 k = *(const float2*)(H + (size_t)i * 128 + lane * 2);
    d[ii] = a.x * k.x + a.y * k.y;
  }
#pragma unroll
  for (int off = 32; off > 0; off >>= 1)
#pragma unroll
    for (int ii = 0; ii < 4; ++ii) d[ii] += __shfl_down(d[ii], off, 64);

  float ce_sum = 0.f, nv = 0.f;
  if (lane == 0) {
#pragma unroll
    for (int ii = 0; ii < 4; ++ii) {
      int i = abase + ii;
      if (targets[i / 3] != 0) {
        int arow = (i / 3) * 4 + (i % 3);
        ce_sum += 100.0f / scale[arow] + __logf(sumexp[i]) - d[ii] * scale[i];
        nv += 1.0f;
      }
    }
  }
  __shared__ float buf[2][4];
  __shared__ int isLast;
  if (lane == 0) { buf[0][w] = ce_sum; buf[1][w] = nv; }
  __syncthreads();
  if (threadIdx.x == 0) {
    float pce = buf[0][0] + buf[0][1] + buf[0][2] + buf[0][3];
    float pnv = buf[1][0] + buf[1][1] + buf[1][2] + buf[1][3];
    __hip_atomic_store(&Pce[blockIdx.x], pce, __ATOMIC_RELAXED, __HIP_MEMORY_SCOPE_AGENT);
    __hip_atomic_store(&Pnv[blockIdx.x], pnv, __ATOMIC_RELAXED, __HIP_MEMORY_SCOPE_AGENT);
    __threadfence();
    uint prev = __hip_atomic_fetch_add(cnt, 1u, __ATOMIC_ACQ_REL, __HIP_MEMORY_SCOPE_AGENT);
    isLast = (prev == gridDim.x - 1);
  }
  __syncthreads();
  if (!isLast) return;

  int t = threadIdx.x;
  float a = 0.f, b = 0.f, c = 0.f, e = 0.f;
#pragma unroll
  for (int j = 0; j < 4; ++j) {
    a += __hip_atomic_load(&Pspike[t + j * 256], __ATOMIC_RELAXED, __HIP_MEMORY_SCOPE_AGENT);
    b += __hip_atomic_load(&Pmem[t + j * 256], __ATOMIC_RELAXED, __HIP_MEMORY_SCOPE_AGENT);
  }
#pragma unroll
  for (int j = 0; j < 3; ++j) {
    c += __hip_atomic_load(&Pce[t + j * 256], __ATOMIC_RELAXED, __HIP_MEMORY_SCOPE_AGENT);
    e += __hip_atomic_load(&Pnv[t + j * 256], __ATOMIC_RELAXED, __HIP_MEMORY_SCOPE_AGENT);
  }
  a = waveRedSum(a); b = waveRedSum(b); c = waveRedSum(c); e = waveRedSum(e);
  __shared__ float fb2[4][4];
  if (lane == 0) { fb2[0][w] = a; fb2[1][w] = b; fb2[2][w] = c; fb2[3][w] = e; }
  __syncthreads();
  if (t == 0) {
    float ssp = fb2[0][0] + fb2[0][1] + fb2[0][2] + fb2[0][3];
    float smm = fb2[1][0] + fb2[1][1] + fb2[1][2] + fb2[1][3];
    float ce  = fb2[2][0] + fb2[2][1] + fb2[2][2] + fb2[2][3];
    float nvt = fb2[3][0] + fb2[3][1] + fb2[3][2] + fb2[3][3];
    float spike_rate = ssp / (float)ELEM;
    float dr = spike_rate - 0.02f;
    float spike_reg = dr * dr;
    float mem_reg = smm / (float)ELEM;
    float tcl = ce / fmaxf(nvt, 1.0f);
    out[0] = tcl + 0.01f * spike_reg + 0.001f * mem_reg;
    out[1] = tcl;
    out[2] = spike_reg;
    out[3] = mem_reg;
    out[4] = spike_rate;
  }
}

extern "C" void kernel_launch(void* const* d_in, const int* in_sizes, int n_in,
                              void* d_out, int out_size, void* d_ws, size_t ws_size,
                              hipStream_t stream) {
  const float* H = (const float*)d_in[0];
  const int* targets = (const int*)d_in[1];
  const float* spikes = (const float*)d_in[2];
  const float* mem = (const float*)d_in[3];
  float* out = (float*)d_out;
  float* ws = (float*)d_ws;

  float* sumexp = ws;                      // [0, 12288)
  uint*  cnt    = (uint*)(ws + 12288);     // [12288]
  float* scale  = ws + 12296;              // +16384 -> 28680
  float* Pspike = ws + 28680;              // +1024  -> 29704
  float* Pmem   = ws + 29704;              // +1024  -> 30728
  float* Pce    = ws + 30728;              // +768   -> 31496
  float* Pnv    = ws + 31496;              // +768   -> 32264
  uint*  Ksw    = (uint*)(ws + 32264);     // M*64 uints (16B aligned)

  hipMemsetAsync(ws, 0, 12292 * sizeof(float), stream);  // sumexp + cnt
  k_prep<<<1024, 256, 0, stream>>>(H, spikes, mem, Ksw, scale, Pspike, Pmem);
  dim3 g2(KSPLIT, NANCH / 128);
  k_sim<<<g2, 256, 0, stream>>>((const uint4*)Ksw, scale, sumexp);
  k_fin<<<NANCH / 16, 256, 0, stream>>>(H, scale, sumexp, targets, Pce, Pnv,
                                        Pspike, Pmem, cnt, out);
}